// Round 1
// 561.075 us; speedup vs baseline: 1.1337x; 1.1337x over previous
//
#include <hip/hip_runtime.h>

// ---------------------------------------------------------------------------
// LlamaAttention_Tender: hidden(2048x4096) -> QKV proj -> RoPE -> int8 qdq(K,V)
// -> GQA causal attention (32 q-heads, 8 kv-heads, D=128) -> out proj.
// All matmuls via bf16 16x16x32 MFMA, fp32 accum. fp32 inputs cast to bf16.
// R3: attention rewritten as LDS-staged double-buffered flash loop:
//     KVBLK=64; K[64][128] + Vt[128][64] tiles staged via global_load_lds
//     (shared by all 4 waves -> 4x less L2 traffic), double-buffered with the
//     2-phase T3 recipe (stage t+1 -> compute t -> __syncthreads drain).
//     XOR-swizzle ((row&7)<<4)^(((row>>3)&1)<<5) on K/Vt/Ps applied BOTH
//     sides (pre-swizzled global src, swizzled ds_read) -> conflict-free
//     b128 reads. LDS = exactly 80 KB -> 2 blocks/CU. setprio(1) on MFMA.
// ---------------------------------------------------------------------------

#define S_LEN 2048
#define HID 4096
#define NH 32
#define NKV 8
#define HD 128
#define QKV_N 6144   // 4096 q + 1024 k + 1024 v

typedef __bf16 bf16x8 __attribute__((ext_vector_type(8)));
typedef float f32x4 __attribute__((ext_vector_type(4)));

__device__ __forceinline__ unsigned short f2b(float f) {
  unsigned int u = __float_as_uint(f);
  u += 0x7fffu + ((u >> 16) & 1u);   // round-to-nearest-even
  return (unsigned short)(u >> 16);
}
__device__ __forceinline__ float b2f(unsigned short h) {
  return __uint_as_float(((unsigned int)h) << 16);
}
// async global->LDS, 16B per lane. LDS dst must be wave-uniform (lane*16 implicit).
__device__ __forceinline__ void gl_lds16(const void* g, void* l) {
  __builtin_amdgcn_global_load_lds(
      (__attribute__((address_space(1))) void*)g,
      (__attribute__((address_space(3))) void*)l, 16, 0, 0);
}
// LDS bank-spread swizzle: permutes 16B chunks within a row; involution.
__device__ __forceinline__ int swz(int row) {
  return ((row & 7) << 4) ^ (((row >> 3) & 1) << 5);
}

// ---------------------------------------------------------------- cast fp32->bf16
__global__ __launch_bounds__(256) void cast_kernel(const float* __restrict__ src,
                                                   unsigned short* __restrict__ dst,
                                                   int n4) {
  int i = blockIdx.x * 256 + threadIdx.x;
  if (i >= n4) return;
  float4 v = ((const float4*)src)[i];
  ushort4 o;
  o.x = f2b(v.x); o.y = f2b(v.y); o.z = f2b(v.z); o.w = f2b(v.w);
  ((ushort4*)dst)[i] = o;
}

// ------------------------------------------------------- B^T GEMM (m97 structure)
// C[M,N] = A[M,K] * B[N,K]^T, 128x128 tile, BK=32, 256 thr (4 waves, 64x64 each).
template <int OUT_BF16>
__global__ __launch_bounds__(256) void gemm_bt(const unsigned short* __restrict__ A,
                                               const unsigned short* __restrict__ B,
                                               void* __restrict__ Cout,
                                               int M, int N, int K) {
  __shared__ __align__(16) unsigned short As[128 * 32];
  __shared__ __align__(16) unsigned short Bs[128 * 32];
  const int tid = threadIdx.x;
  const int lane = tid & 63, wave = tid >> 6;
  const int quad = lane >> 4, l16 = lane & 15;
  const long row0 = (long)blockIdx.y * 128;
  const long col0 = (long)blockIdx.x * 128;
  const int wr = (wave >> 1) * 64, wc = (wave & 1) * 64;

  f32x4 acc[4][4] = {};

  // staging map: call c covers flat elems [c*2048, c*2048+2048), 8 elems/lane
  const int e0 = tid * 8;
  const int r0s = e0 >> 5, c0s = e0 & 31;
  const int r1s = (e0 + 2048) >> 5;  // c1s == c0s
  const unsigned short* Ap0 = A + (row0 + r0s) * (long)K + c0s;
  const unsigned short* Ap1 = A + (row0 + r1s) * (long)K + c0s;
  const unsigned short* Bp0 = B + (col0 + r0s) * (long)K + c0s;
  const unsigned short* Bp1 = B + (col0 + r1s) * (long)K + c0s;
  unsigned short* AsD0 = As + wave * 512;
  unsigned short* AsD1 = As + 2048 + wave * 512;
  unsigned short* BsD0 = Bs + wave * 512;
  unsigned short* BsD1 = Bs + 2048 + wave * 512;

  for (int k0 = 0; k0 < K; k0 += 32) {
    __syncthreads();
    gl_lds16(Ap0 + k0, AsD0);
    gl_lds16(Ap1 + k0, AsD1);
    gl_lds16(Bp0 + k0, BsD0);
    gl_lds16(Bp1 + k0, BsD1);
    __syncthreads();
    bf16x8 af[4], bf[4];
#pragma unroll
    for (int mi = 0; mi < 4; ++mi)
      af[mi] = *(const bf16x8*)&As[(wr + mi * 16 + l16) * 32 + quad * 8];
#pragma unroll
    for (int ni = 0; ni < 4; ++ni)
      bf[ni] = *(const bf16x8*)&Bs[(wc + ni * 16 + l16) * 32 + quad * 8];
#pragma unroll
    for (int mi = 0; mi < 4; ++mi)
#pragma unroll
      for (int ni = 0; ni < 4; ++ni)
        acc[mi][ni] = __builtin_amdgcn_mfma_f32_16x16x32_bf16(af[mi], bf[ni], acc[mi][ni], 0, 0, 0);
  }
#pragma unroll
  for (int mi = 0; mi < 4; ++mi)
#pragma unroll
    for (int ni = 0; ni < 4; ++ni)
#pragma unroll
      for (int r = 0; r < 4; ++r) {
        long row = row0 + wr + mi * 16 + quad * 4 + r;
        long col = col0 + wc + ni * 16 + l16;
        float v = acc[mi][ni][r];
        if (OUT_BF16) ((unsigned short*)Cout)[row * N + col] = f2b(v);
        else          ((float*)Cout)[row * N + col] = v;
      }
}

// ------------------------------------------- RoPE + sym int8 quant-dequant + split
// qkv[2048][6144] bf16 -> Qb[32][2048][128], Kb[8][2048][128], Vb[8][2048][128]
__global__ __launch_bounds__(256) void postproc(const unsigned short* __restrict__ qkv,
                                                const int* __restrict__ pos_ids,
                                                unsigned short* __restrict__ Qb,
                                                unsigned short* __restrict__ Kb,
                                                unsigned short* __restrict__ Vb) {
  const int s = blockIdx.x;
  const int lane = threadIdx.x & 63, wave = threadIdx.x >> 6;
  const float pos = (float)pos_ids[s];
  // inv_freq = 10000^(-lane/64) = exp(-lane * ln(10000)/64); pair (d, d+64)
  const float invf = expf(-(float)lane * 0.14391156831212787f);
  const float ang = pos * invf;
  const float ca = cosf(ang), sa = sinf(ang);

  for (int r = wave; r < 48; r += 4) {
    if (r < 32) {                 // Q head r: rope only
      const unsigned short* src = qkv + (long)s * QKV_N + r * HD;
      float x0 = b2f(src[lane]), x1 = b2f(src[lane + 64]);
      unsigned short* dst = Qb + ((long)r * S_LEN + s) * HD;
      dst[lane]      = f2b(x0 * ca - x1 * sa);
      dst[lane + 64] = f2b(x1 * ca + x0 * sa);
    } else if (r < 40) {          // K head r-32: rope then quant-dequant
      int h = r - 32;
      const unsigned short* src = qkv + (long)s * QKV_N + 4096 + h * HD;
      float x0 = b2f(src[lane]), x1 = b2f(src[lane + 64]);
      float y0 = x0 * ca - x1 * sa;
      float y1 = x1 * ca + x0 * sa;
      float m = fmaxf(fabsf(y0), fabsf(y1));
      for (int off = 32; off; off >>= 1) m = fmaxf(m, __shfl_xor(m, off, 64));
      float scale = fmaxf(m / 127.0f, 1e-9f);
      float q0 = fminf(fmaxf(rintf(y0 / scale), -128.f), 127.f);
      float q1 = fminf(fmaxf(rintf(y1 / scale), -128.f), 127.f);
      unsigned short* dst = Kb + ((long)h * S_LEN + s) * HD;
      dst[lane]      = f2b(q0 * scale);
      dst[lane + 64] = f2b(q1 * scale);
    } else {                      // V head r-40: quant-dequant only
      int h = r - 40;
      const unsigned short* src = qkv + (long)s * QKV_N + 5120 + h * HD;
      float x0 = b2f(src[lane]), x1 = b2f(src[lane + 64]);
      float m = fmaxf(fabsf(x0), fabsf(x1));
      for (int off = 32; off; off >>= 1) m = fmaxf(m, __shfl_xor(m, off, 64));
      float scale = fmaxf(m / 127.0f, 1e-9f);
      float q0 = fminf(fmaxf(rintf(x0 / scale), -128.f), 127.f);
      float q1 = fminf(fmaxf(rintf(x1 / scale), -128.f), 127.f);
      unsigned short* dst = Vb + ((long)h * S_LEN + s) * HD;
      dst[lane]      = f2b(q0 * scale);
      dst[lane + 64] = f2b(q1 * scale);
    }
  }
}

// -------------------------------------------------- V transpose: [h][s][d]->[h][d][s]
__global__ __launch_bounds__(256) void transpose_v(const unsigned short* __restrict__ Vb,
                                                   unsigned short* __restrict__ Vtb) {
  __shared__ unsigned short t[64][136];
  const int h = blockIdx.x >> 5, st = blockIdx.x & 31;
  const int tid = threadIdx.x;
  const long vbase = (long)h * S_LEN * HD;
#pragma unroll
  for (int p = 0; p < 8; ++p) {
    int e = p * 1024 + tid * 4;
    int sl = e >> 7, d = e & 127;
    ushort4 v = *(const ushort4*)(Vb + vbase + (long)(st * 64 + sl) * HD + d);
    t[sl][d] = v.x; t[sl][d + 1] = v.y; t[sl][d + 2] = v.z; t[sl][d + 3] = v.w;
  }
  __syncthreads();
  const long tbase = (long)h * HD * S_LEN;
#pragma unroll
  for (int p = 0; p < 8; ++p) {
    int o = p * 1024 + tid * 4;
    int d = o >> 6, sl = o & 63;
    ushort4 v;
    v.x = t[sl][d]; v.y = t[sl + 1][d]; v.z = t[sl + 2][d]; v.w = t[sl + 3][d];
    *(ushort4*)(Vtb + tbase + (long)d * S_LEN + st * 64 + sl) = v;
  }
}

// ------------------------------------------------------------- flash attention
// Block = (head, 128-row q-tile), 4 waves x 32 q-rows. KVBLK=64.
// K tile [64 keys][128 d] and Vt tile [128 d][64 keys] staged in LDS via
// global_load_lds (shared by all waves), double-buffered 2-phase:
//   barrier(drains prev stage) -> issue stage(t+1) -> compute(t).
// XOR swizzle on K/Vt/Ps rows applied on BOTH the pre-swizzled global source
// (linear LDS dest, rule #21) and the ds_read/ds_write side -> conflict-free.
// LDS: K 2x16K + Vt 2x16K + Ps 16K = 80 KB exactly -> 2 blocks/CU.
// Complementary qt pairing: steps/pair = (2qt+2)+(2(15-qt)+2) = 34, balanced.
__global__ __launch_bounds__(256, 2) void attn_kernel(const unsigned short* __restrict__ Qb,
                                                      const unsigned short* __restrict__ Kb,
                                                      const unsigned short* __restrict__ Vtb,
                                                      unsigned short* __restrict__ Ob) {
  __shared__ __align__(16) char lds[81920];
  // layout: K buf0 @0, K buf1 @16384, V buf0 @32768, V buf1 @49152, Ps @65536

  const int bx = blockIdx.x;
  const int p8 = bx & 1;
  const int g = (bx >> 1) & 7;
  const int b8 = bx >> 8;
  const int qt = (p8 ^ b8) ? (15 - g) : g;
  const int h = ((bx >> 4) & 15) + 16 * b8;
  const int hk = h >> 2;                        // GQA: 4 q-heads per kv-head
  const int tid = threadIdx.x;
  const int lane = tid & 63, wave = tid >> 6;
  const int quad = lane >> 4, l16 = lane & 15;

  // Q fragments for this wave's 32 rows (A-operand layout), from global
  bf16x8 qf[2][4];
  {
    const unsigned short* qb =
        Qb + ((long)h * S_LEN + qt * 128 + wave * 32 + l16) * HD + quad * 8;
#pragma unroll
    for (int mi = 0; mi < 2; ++mi)
#pragma unroll
      for (int ks = 0; ks < 4; ++ks)
        qf[mi][ks] = *(const bf16x8*)(qb + mi * 16 * HD + ks * 32);
  }

  f32x4 O[2][8] = {};
  float mrow[2][4], lrow[2][4];
#pragma unroll
  for (int mi = 0; mi < 2; ++mi)
#pragma unroll
    for (int r = 0; r < 4; ++r) { mrow[mi][r] = -1e30f; lrow[mi][r] = 0.f; }

  const char* Kg = (const char*)(Kb + (long)hk * S_LEN * HD);
  const char* Vg = (const char*)(Vtb + (long)hk * HD * S_LEN);
  char* PsB = lds + 65536;
  const float sscale = 0.08838834764831845f;  // 1/sqrt(128)
  const int nsteps = 2 * qt + 2;              // 64-key steps

  // stage one 64-key K tile (16 KB, contiguous rows in global) into buf
  auto stageK = [&](int step, int buf) {
    char* dst = lds + buf * 16384 + wave * 1024;
    const char* src = Kg + (long)step * 16384;
#pragma unroll
    for (int c = 0; c < 4; ++c) {
      int f = c * 4096 + tid * 16;
      int row = f >> 8, wb = f & 255;
      gl_lds16(src + row * 256 + (wb ^ swz(row)), dst + c * 4096);
    }
  };
  // stage one Vt tile [128 d][64 keys] (d-rows strided 4096B in global)
  auto stageV = [&](int step, int buf) {
    char* dst = lds + 32768 + buf * 16384 + wave * 1024;
    const char* src = Vg + (long)step * 128;
#pragma unroll
    for (int c = 0; c < 4; ++c) {
      int f = c * 4096 + tid * 16;
      int d = f >> 7, wb = f & 127;
      gl_lds16(src + (long)d * (S_LEN * 2) + (wb ^ swz(d)), dst + c * 4096);
    }
  };

  stageK(0, 0);
  stageV(0, 0);

  for (int t = 0; t < nsteps; ++t) {
    __syncthreads();   // drains this wave's stage (vmcnt 0) + syncs all waves
    if (t + 1 < nsteps) {
      stageK(t + 1, (t + 1) & 1);
      stageV(t + 1, (t + 1) & 1);
    }
    const char* Ks = lds + (t & 1) * 16384;
    const char* Vs = lds + 32768 + (t & 1) * 16384;

    // ---- S = Q K^T over 64 keys (4 ni of 16)
    f32x4 S[2][4] = {};
    __builtin_amdgcn_s_setprio(1);
#pragma unroll
    for (int ni = 0; ni < 4; ++ni) {
      const int row = ni * 16 + l16;
      const char* kr = Ks + row * 256;
      const int sw = swz(row);
      const int q16 = quad * 16;
      bf16x8 kf0 = *(const bf16x8*)(kr + ((q16 + 0)   ^ sw));
      bf16x8 kf1 = *(const bf16x8*)(kr + ((q16 + 64)  ^ sw));
      bf16x8 kf2 = *(const bf16x8*)(kr + ((q16 + 128) ^ sw));
      bf16x8 kf3 = *(const bf16x8*)(kr + ((q16 + 192) ^ sw));
      S[0][ni] = __builtin_amdgcn_mfma_f32_16x16x32_bf16(qf[0][0], kf0, S[0][ni], 0, 0, 0);
      S[1][ni] = __builtin_amdgcn_mfma_f32_16x16x32_bf16(qf[1][0], kf0, S[1][ni], 0, 0, 0);
      S[0][ni] = __builtin_amdgcn_mfma_f32_16x16x32_bf16(qf[0][1], kf1, S[0][ni], 0, 0, 0);
      S[1][ni] = __builtin_amdgcn_mfma_f32_16x16x32_bf16(qf[1][1], kf1, S[1][ni], 0, 0, 0);
      S[0][ni] = __builtin_amdgcn_mfma_f32_16x16x32_bf16(qf[0][2], kf2, S[0][ni], 0, 0, 0);
      S[1][ni] = __builtin_amdgcn_mfma_f32_16x16x32_bf16(qf[1][2], kf2, S[1][ni], 0, 0, 0);
      S[0][ni] = __builtin_amdgcn_mfma_f32_16x16x32_bf16(qf[0][3], kf3, S[0][ni], 0, 0, 0);
      S[1][ni] = __builtin_amdgcn_mfma_f32_16x16x32_bf16(qf[1][3], kf3, S[1][ni], 0, 0, 0);
    }
    __builtin_amdgcn_s_setprio(0);

    // ---- scale + causal mask + row max
    const bool diag = (t >= 2 * qt);
    const int qrow_base = qt * 128 + wave * 32;
    float rmax[2][4];
#pragma unroll
    for (int mi = 0; mi < 2; ++mi)
#pragma unroll
      for (int r = 0; r < 4; ++r) rmax[mi][r] = -1e30f;
#pragma unroll
    for (int mi = 0; mi < 2; ++mi)
#pragma unroll
      for (int ni = 0; ni < 4; ++ni) {
        int col = t * 64 + ni * 16 + l16;
#pragma unroll
        for (int r = 0; r < 4; ++r) {
          int row = qrow_base + mi * 16 + quad * 4 + r;
          float v = S[mi][ni][r] * sscale;
          if (diag && col > row) v = -1e9f;
          S[mi][ni][r] = v;
          rmax[mi][r] = fmaxf(rmax[mi][r], v);
        }
      }
    float alpha[2][4], rsum[2][4];
#pragma unroll
    for (int mi = 0; mi < 2; ++mi)
#pragma unroll
      for (int r = 0; r < 4; ++r) {
        float v = rmax[mi][r];
        v = fmaxf(v, __shfl_xor(v, 1, 64));
        v = fmaxf(v, __shfl_xor(v, 2, 64));
        v = fmaxf(v, __shfl_xor(v, 4, 64));
        v = fmaxf(v, __shfl_xor(v, 8, 64));
        float mnew = fmaxf(mrow[mi][r], v);
        alpha[mi][r] = __expf(mrow[mi][r] - mnew);
        mrow[mi][r] = mnew;
        rsum[mi][r] = 0.f;
      }

    // ---- P = exp(S - m) -> wave-local swizzled LDS rows, accumulate sums
#pragma unroll
    for (int mi = 0; mi < 2; ++mi)
#pragma unroll
      for (int ni = 0; ni < 4; ++ni)
#pragma unroll
        for (int r = 0; r < 4; ++r) {
          float p = __expf(S[mi][ni][r] - mrow[mi][r]);
          rsum[mi][r] += p;
          int prow = wave * 32 + mi * 16 + quad * 4 + r;
          int pcol2 = (ni * 16 + l16) * 2;
          *(unsigned short*)(PsB + prow * 128 + (pcol2 ^ swz(prow))) = f2b(p);
        }
#pragma unroll
    for (int mi = 0; mi < 2; ++mi)
#pragma unroll
      for (int r = 0; r < 4; ++r) {
        float v = rsum[mi][r];
        v += __shfl_xor(v, 1, 64);
        v += __shfl_xor(v, 2, 64);
        v += __shfl_xor(v, 4, 64);
        v += __shfl_xor(v, 8, 64);
        lrow[mi][r] = lrow[mi][r] * alpha[mi][r] + v;
      }
#pragma unroll
    for (int mi = 0; mi < 2; ++mi)
#pragma unroll
      for (int ni = 0; ni < 8; ++ni)
#pragma unroll
        for (int r = 0; r < 4; ++r) O[mi][ni][r] *= alpha[mi][r];

    // ---- O += P V : P A-frags from wave-local LDS, Vt B-frags from LDS tile
    bf16x8 pf[2][2];
#pragma unroll
    for (int mi = 0; mi < 2; ++mi)
#pragma unroll
      for (int ks2 = 0; ks2 < 2; ++ks2) {
        int prow = wave * 32 + mi * 16 + l16;
        pf[mi][ks2] = *(const bf16x8*)(PsB + prow * 128 +
                                       ((ks2 * 64 + quad * 16) ^ swz(prow)));
      }
    __builtin_amdgcn_s_setprio(1);
#pragma unroll
    for (int ni = 0; ni < 8; ++ni) {
      const int row = ni * 16 + l16;
      const char* vr = Vs + row * 128;
      const int sw = swz(row);
      const int q16 = quad * 16;
      bf16x8 vf0 = *(const bf16x8*)(vr + ((q16 + 0)  ^ sw));
      bf16x8 vf1 = *(const bf16x8*)(vr + ((q16 + 64) ^ sw));
      O[0][ni] = __builtin_amdgcn_mfma_f32_16x16x32_bf16(pf[0][0], vf0, O[0][ni], 0, 0, 0);
      O[1][ni] = __builtin_amdgcn_mfma_f32_16x16x32_bf16(pf[1][0], vf0, O[1][ni], 0, 0, 0);
      O[0][ni] = __builtin_amdgcn_mfma_f32_16x16x32_bf16(pf[0][1], vf1, O[0][ni], 0, 0, 0);
      O[1][ni] = __builtin_amdgcn_mfma_f32_16x16x32_bf16(pf[1][1], vf1, O[1][ni], 0, 0, 0);
    }
    __builtin_amdgcn_s_setprio(0);
  }

  // normalize + store bf16 at [s][h*128+d]
#pragma unroll
  for (int mi = 0; mi < 2; ++mi)
#pragma unroll
    for (int r = 0; r < 4; ++r) {
      float inv = 1.0f / lrow[mi][r];
      long srow = qt * 128 + wave * 32 + mi * 16 + quad * 4 + r;
#pragma unroll
      for (int ni = 0; ni < 8; ++ni) {
        long col = (long)h * HD + ni * 16 + l16;
        Ob[srow * (long)HID + col] = f2b(O[mi][ni][r] * inv);
      }
    }
}

// ---------------------------------------------------------------------------
extern "C" void kernel_launch(void* const* d_in, const int* in_sizes, int n_in,
                              void* d_out, int out_size, void* d_ws, size_t ws_size,
                              hipStream_t stream) {
  const float* hidden = (const float*)d_in[0];
  const float* wq = (const float*)d_in[1];
  const float* wk = (const float*)d_in[2];
  const float* wv = (const float*)d_in[3];
  const float* wo = (const float*)d_in[4];
  const int* pos = (const int*)d_in[5];
  float* out = (float*)d_out;

  // workspace layout (bytes); total 138,412,032. Overlays: Qb=hid_b (hid dead
  // after GEMM1), attn_b=qkv_b (qkv dead after postproc).
  char* ws = (char*)d_ws;
  unsigned short* wqkv_b = (unsigned short*)(ws);               // 50,331,648
  unsigned short* wo_b   = (unsigned short*)(ws + 50331648);    // 33,554,432
  unsigned short* hid_b  = (unsigned short*)(ws + 83886080);    // 16,777,216
  unsigned short* qkv_b  = (unsigned short*)(ws + 100663296);   // 25,165,824
  unsigned short* Kb     = (unsigned short*)(ws + 125829120);   //  4,194,304
  unsigned short* Vb     = (unsigned short*)(ws + 130023424);   //  4,194,304
  unsigned short* Vtb    = (unsigned short*)(ws + 134217728);   //  4,194,304
  unsigned short* Qb     = hid_b;
  unsigned short* attn_b = qkv_b;

  cast_kernel<<<8388608 / 1024, 256, 0, stream>>>(hidden, hid_b, 8388608 / 4);
  cast_kernel<<<16777216 / 1024, 256, 0, stream>>>(wq, wqkv_b, 16777216 / 4);
  cast_kernel<<<4194304 / 1024, 256, 0, stream>>>(wk, wqkv_b + 16777216, 4194304 / 4);
  cast_kernel<<<4194304 / 1024, 256, 0, stream>>>(wv, wqkv_b + 20971520, 4194304 / 4);
  cast_kernel<<<16777216 / 1024, 256, 0, stream>>>(wo, wo_b, 16777216 / 4);

  gemm_bt<1><<<dim3(QKV_N / 128, S_LEN / 128), 256, 0, stream>>>(
      hid_b, wqkv_b, (void*)qkv_b, S_LEN, QKV_N, HID);

  postproc<<<S_LEN, 256, 0, stream>>>(qkv_b, pos, Qb, Kb, Vb);
  transpose_v<<<NKV * 32, 256, 0, stream>>>(Vb, Vtb);
  attn_kernel<<<NH * 16, 256, 0, stream>>>(Qb, Kb, Vtb, attn_b);

  gemm_bt<0><<<dim3(HID / 128, S_LEN / 128), 256, 0, stream>>>(
      attn_b, wo_b, (void*)out, S_LEN, HID, HID);
}